// Round 11
// baseline (35.768 us; speedup 1.0000x reference)
//
#include <hip/hip_runtime.h>

// GraphUpSamplingLayer: 3-D k=1 NN argmin + batched feature gather.
// B=4, C=512, M=2048 (coarse points), N=8192 (dense points), D=3.
constexpr int B = 4;
constexpr int C = 512;
constexpr int M = 2048;
constexpr int N = 8192;

// ---------------------------------------------------------------------------
// v9 argmin: per-lane candidate reads amortized over Q=8 wave-uniform queries.
//
// Measured ladder: v2/v8 (uniform-broadcast reads) = 17/20.6us -> LDS-issue-
// bound (1 ds_read_b128 per candidate-wave = 4096/CU x 12cyc ~= 20us).
// v6 (per-lane reads, Q=4) = 23us with VGPR squeezed to 32 by (512,8).
// v9: each ds_read_b128 feeds 64 lanes x 8 queries = 512 pairs:
//   LDS:  512 reads/CU x 12 cyc ~= 2.6us
//   VALU: 6 ops/pair -> ~5.5us/SIMD (4 waves/SIMD, overlaps LDS)
//   (512,4): VGPR cap 128 (est ~60) -- no squeeze, no spill; named scalars.
// Block = 512 thr = 8 waves; wave w owns queries [n0+8w, n0+8w+8) (uniform);
// lane l owns candidate slice {i*64+l}; 32 iters, 1-deep prefetch.
// Score = ||s||^2/2 - p.s (h in float4.w): 3 fma + cmp + 2 cndmask
// (validated absmax 0.0 across R7-R10).
// Tie-break = jnp first-occurrence (validated in v6/R8): in-lane m-ascending
// strict <; cross-lane lexicographic (d, m) full-wave shfl reduce.
// ---------------------------------------------------------------------------
#define DEF_Q(k) float px##k, py##k, pz##k, bb##k = 1e30f; int mm##k = 0;
#define LOAD_Q(k) px##k = pp[3*k]; py##k = pp[3*k+1]; pz##k = pp[3*k+2];
#define STEP(k) { float s = fmaf(-cc.x, px##k, cc.w);                       \
                  s = fmaf(-cc.y, py##k, s);                                \
                  s = fmaf(-cc.z, pz##k, s);                                \
                  const bool lt = s < bb##k;                                \
                  bb##k = lt ? s : bb##k;                                   \
                  mm##k = lt ? m : mm##k; }
#define RED(k) { const float ob = __shfl_xor(bb##k, off, 64);               \
                 const int   om = __shfl_xor(mm##k, off, 64);               \
                 if (ob < bb##k || (ob == bb##k && om < mm##k)) {           \
                     bb##k = ob; mm##k = om; } }

__global__ __launch_bounds__(512, 4) void nn_argmin_v9(
    const float* __restrict__ pos,      // [B][N][3]
    const float* __restrict__ sub_pos,  // [B][M][3]
    int* __restrict__ idx_out)          // [B][N]
{
    __shared__ float4 sp[M];            // 32 KB: (x, y, z, ||s||^2/2)

    const int b  = blockIdx.x >> 7;     // 128 blocks per batch
    const int n0 = (blockIdx.x & 127) << 6;  // 64 queries per block
    const int t  = threadIdx.x;
    const int w    = t >> 6;            // wave 0..7, owns 8 queries
    const int lane = t & 63;            // candidate slice {i*64+lane}

    const float* spb = sub_pos + (size_t)b * (M * 3);
    #pragma unroll
    for (int i = t; i < M; i += 512) {
        const float x = spb[i * 3 + 0];
        const float y = spb[i * 3 + 1];
        const float z = spb[i * 3 + 2];
        sp[i] = make_float4(x, y, z, 0.5f * fmaf(z, z, fmaf(y, y, x * x)));
    }
    __syncthreads();

    // 8 wave-uniform queries (same addresses in every lane -> broadcast loads).
    const float* pp = pos + ((size_t)b * N + n0 + (w << 3)) * 3;
    DEF_Q(0) DEF_Q(1) DEF_Q(2) DEF_Q(3) DEF_Q(4) DEF_Q(5) DEF_Q(6) DEF_Q(7)
    LOAD_Q(0) LOAD_Q(1) LOAD_Q(2) LOAD_Q(3)
    LOAD_Q(4) LOAD_Q(5) LOAD_Q(6) LOAD_Q(7)

    float4 c = sp[lane];                // 1-deep prefetch, iter 0
    #pragma unroll 4
    for (int i = 0; i < 32; ++i) {
        const float4 cc = c;
        c = sp[((((i + 1) & 31) << 6) + lane)];   // prefetch next (wraps, ok)
        const int m = (i << 6) + lane;
        STEP(0) STEP(1) STEP(2) STEP(3) STEP(4) STEP(5) STEP(6) STEP(7)
    }

    // Full-wave lexicographic (d, m) argmin reduce == jnp first-occurrence.
    #pragma unroll
    for (int off = 1; off < 64; off <<= 1) {
        RED(0) RED(1) RED(2) RED(3) RED(4) RED(5) RED(6) RED(7)
    }

    if (lane == 0) {
        int* o = idx_out + (size_t)b * N + n0 + (w << 3);
        o[0] = mm0; o[1] = mm1; o[2] = mm2; o[3] = mm3;
        o[4] = mm4; o[5] = mm5; o[6] = mm6; o[7] = mm7;
    }
}

// ---------------------------------------------------------------------------
// Phase 2: out[b][c][n] = sub_x[b][c][idx[b][n]]
// 84 MB HBM in ~11.7us = 7.2 TB/s effective -- at/above the copy ceiling.
// ---------------------------------------------------------------------------
__global__ __launch_bounds__(256) void gather_kernel(
    const float* __restrict__ sub_x,  // [B][C][M]
    const int* __restrict__ idx,      // [B][N]
    float* __restrict__ out)          // [B][C][N]
{
    __shared__ float row[M];          // 8 KB

    const int b = blockIdx.x >> 9;    // C = 512
    const int c = blockIdx.x & 511;
    const int t = threadIdx.x;

    const float* rsrc = sub_x + ((size_t)b * C + c) * M;
    for (int i = t; i < M; i += 256) row[i] = rsrc[i];
    __syncthreads();

    const int4* iv = (const int4*)(idx + (size_t)b * N);
    float4* ov = (float4*)(out + ((size_t)b * C + c) * N);
    #pragma unroll
    for (int i = t; i < N / 4; i += 256) {
        const int4 ii = iv[i];
        float4 v;
        v.x = row[ii.x];
        v.y = row[ii.y];
        v.z = row[ii.z];
        v.w = row[ii.w];
        ov[i] = v;
    }
}

extern "C" void kernel_launch(void* const* d_in, const int* in_sizes, int n_in,
                              void* d_out, int out_size, void* d_ws, size_t ws_size,
                              hipStream_t stream) {
    const float* sub_x   = (const float*)d_in[0];  // [B][C][M]
    const float* sub_pos = (const float*)d_in[1];  // [B][M][3]
    const float* pos     = (const float*)d_in[2];  // [B][N][3]
    float* out = (float*)d_out;                    // [B][C][N]
    int* idx = (int*)d_ws;                         // B*N*4 = 128 KB scratch

    nn_argmin_v9<<<B * (N / 64), 512, 0, stream>>>(pos, sub_pos, idx);
    gather_kernel<<<B * C, 256, 0, stream>>>(sub_x, idx, out);
}